// Round 2
// 740.156 us; speedup vs baseline: 1.1007x; 1.1007x over previous
//
#include <hip/hip_runtime.h>

// Problem constants (reference: N=2048, H=2048, V=32000)
#define MDIM 2048
#define KDIM 2048
#define VDIM 32000
#define BM 256
#define BN 256
#define BK 64
#define LDAB (2 * KDIM)  // bf16 row stride inside the in-place-cast fp32 buffer

typedef __bf16 bf16x8 __attribute__((ext_vector_type(8)));
typedef float f32x4 __attribute__((ext_vector_type(4)));

__device__ __forceinline__ unsigned short f32_to_bf16_rne(float f) {
    unsigned u = __float_as_uint(f);
    u += 0x7FFFu + ((u >> 16) & 1u);
    return (unsigned short)(u >> 16);
}

// In-place fp32 -> bf16 row compaction, 4 rows per block (unchanged, proven).
__global__ __launch_bounds__(256) void cast_inplace_rows4_kernel(
        float* __restrict__ rows, float* zero_out) {
    if (zero_out && blockIdx.x == 0 && threadIdx.x == 0) *zero_out = 0.0f;
    float* base = rows + (long)blockIdx.x * 4 * KDIM;
    const int t = threadIdx.x;
    float4 v[8];
#pragma unroll
    for (int rr = 0; rr < 4; ++rr) {
        const float4* p = reinterpret_cast<const float4*>(base + rr * KDIM + t * 8);
        v[2 * rr]     = p[0];
        v[2 * rr + 1] = p[1];
    }
    __syncthreads();
#pragma unroll
    for (int rr = 0; rr < 4; ++rr) {
        union { unsigned short h[8]; uint4 u; } r;
        float4 a = v[2 * rr], b = v[2 * rr + 1];
        r.h[0] = f32_to_bf16_rne(a.x);
        r.h[1] = f32_to_bf16_rne(a.y);
        r.h[2] = f32_to_bf16_rne(a.z);
        r.h[3] = f32_to_bf16_rne(a.w);
        r.h[4] = f32_to_bf16_rne(b.x);
        r.h[5] = f32_to_bf16_rne(b.y);
        r.h[6] = f32_to_bf16_rne(b.z);
        r.h[7] = f32_to_bf16_rne(b.w);
        reinterpret_cast<uint4*>(base + rr * KDIM)[t] = r.u;
    }
}

// ---------------------------------------------------------------------------
// 256x256 tile, BK=64, 8-wave (2M x 4N), 8-phase schedule with counted vmcnt.
// LDS: As[2][256][64] + Bs[2][256][64] bf16 = 128 KiB (dbuf, tile t -> buf t&1).
// Per phase: {ds_read subtile, stage 1 half-tile (2x global_load_lds),
//             barrier, lgkmcnt(0), setprio(1), 16 MFMA, setprio(0), barrier}.
// B frags register-resident per K-tile (12 ds_reads at ph0/ph4); A quadrant
// per phase (4 ds_reads). vmcnt(4) ONLY at ph3/ph7 (never 0 in main loop).
//
// Stage schedule (iter i, tiles 2i->buf0 ph0-3, 2i+1->buf1 ph4-7):
//   ph0: T(2i+1).A both halves -> buf1.A  (buf1.A free since prev ph7 barrier)
//   ph1: T(2i+2).B h0 -> buf0.B           (buf0.B last read at ph0: B in regs)
//   ph2: T(2i+2).B h1
//   ph3: no stage; vmcnt(4)  => all but ph1+ph2's 4 loads landed => buf1 ready
//   ph4: T(2i+2).A h0 -> buf0.A           (buf0.A last read at ph3)
//   ph5: T(2i+2).A h1
//   ph6: T(2i+3).B h0 -> buf1.B           (buf1.B last read at ph4: B in regs)
//   ph7: T(2i+3).B h1; vmcnt(4) => all but ph6+ph7's 4 loads => buf0 ready
// Every DMA write lands in a region whose last ds_read is behind a barrier
// that follows every wave's lgkmcnt(0); every first ds_read of staged data is
// behind the counted vmcnt + barrier. Last iter: stage kt clamped to the last
// tile (harmless L2-hot re-reads) so the vmcnt arithmetic has no special case.
//
// XOR swizzle (proven 0 bank conflicts this session): row r stores global
// 16B-seg g at slot g ^ (r&7); fragment readers use the same XOR.
// ---------------------------------------------------------------------------

#define BMFMA(a, b, c) __builtin_amdgcn_mfma_f32_16x16x32_bf16(a, b, c, 0, 0, 0)

#define GLL16(gp, lp) __builtin_amdgcn_global_load_lds( \
    (const __attribute__((address_space(1))) void*)(gp), \
    (__attribute__((address_space(3))) void*)(lp), 16, 0, 0)

#define STAGE_A(bi, hf, kt) do { \
    GLL16(aG0 + (size_t)(hf) * 128 * LDAB + (kt), &As[bi][(hf) * 128 * BK + dOff0]); \
    GLL16(aG1 + (size_t)(hf) * 128 * LDAB + (kt), &As[bi][(hf) * 128 * BK + dOff1]); \
} while (0)

#define STAGE_B(bi, hf, kt) do { \
    GLL16(bG0 + (size_t)(hf) * 128 * LDAB + (kt), &Bs[bi][(hf) * 128 * BK + dOff0]); \
    GLL16(bG1 + (size_t)(hf) * 128 * LDAB + (kt), &Bs[bi][(hf) * 128 * BK + dOff1]); \
} while (0)

#define DS_B1(bi, n) do { \
    const unsigned short* br_ = &Bs[bi][(wcol + (n) * 16 + m0) * BK]; \
    bfr[2 * (n)]     = *(const bf16x8*)(const void*)(br_ + off0); \
    bfr[2 * (n) + 1] = *(const bf16x8*)(const void*)(br_ + off1); \
} while (0)
#define DS_B8(bi) do { DS_B1(bi, 0); DS_B1(bi, 1); DS_B1(bi, 2); DS_B1(bi, 3); } while (0)

#define DS_A2(bi, mb) do { \
    const unsigned short* ar_ = &As[bi][(wrow + (mb) * 16 + m0) * BK]; \
    af[0] = *(const bf16x8*)(const void*)(ar_ + off0); \
    af[1] = *(const bf16x8*)(const void*)(ar_ + off1); \
    af[2] = *(const bf16x8*)(const void*)(ar_ + 16 * BK + off0); \
    af[3] = *(const bf16x8*)(const void*)(ar_ + 16 * BK + off1); \
} while (0)

// 16 MFMA, dependent-acc reuse distance 8.
#define MFMA16(mb) do { \
    acc[(mb)][0]     = BMFMA(af[0], bfr[0], acc[(mb)][0]); \
    acc[(mb) + 1][0] = BMFMA(af[2], bfr[0], acc[(mb) + 1][0]); \
    acc[(mb)][1]     = BMFMA(af[0], bfr[2], acc[(mb)][1]); \
    acc[(mb) + 1][1] = BMFMA(af[2], bfr[2], acc[(mb) + 1][1]); \
    acc[(mb)][2]     = BMFMA(af[0], bfr[4], acc[(mb)][2]); \
    acc[(mb) + 1][2] = BMFMA(af[2], bfr[4], acc[(mb) + 1][2]); \
    acc[(mb)][3]     = BMFMA(af[0], bfr[6], acc[(mb)][3]); \
    acc[(mb) + 1][3] = BMFMA(af[2], bfr[6], acc[(mb) + 1][3]); \
    acc[(mb)][0]     = BMFMA(af[1], bfr[1], acc[(mb)][0]); \
    acc[(mb) + 1][0] = BMFMA(af[3], bfr[1], acc[(mb) + 1][0]); \
    acc[(mb)][1]     = BMFMA(af[1], bfr[3], acc[(mb)][1]); \
    acc[(mb) + 1][1] = BMFMA(af[3], bfr[3], acc[(mb) + 1][1]); \
    acc[(mb)][2]     = BMFMA(af[1], bfr[5], acc[(mb)][2]); \
    acc[(mb) + 1][2] = BMFMA(af[3], bfr[5], acc[(mb) + 1][2]); \
    acc[(mb)][3]     = BMFMA(af[1], bfr[7], acc[(mb)][3]); \
    acc[(mb) + 1][3] = BMFMA(af[3], bfr[7], acc[(mb) + 1][3]); \
} while (0)

#define BAR() do { __builtin_amdgcn_s_barrier(); __builtin_amdgcn_sched_barrier(0); } while (0)
#define WAITKL() do { asm volatile("s_waitcnt lgkmcnt(0)" ::: "memory"); \
                      __builtin_amdgcn_sched_barrier(0); } while (0)
#define VMCNT4() do { asm volatile("s_waitcnt vmcnt(4)" ::: "memory"); \
                      __builtin_amdgcn_sched_barrier(0); } while (0)
#define VMCNT0() do { asm volatile("s_waitcnt vmcnt(0)" ::: "memory"); \
                      __builtin_amdgcn_sched_barrier(0); } while (0)

#define PHASE(dsr, stg, wt, bi, mb) do { \
    dsr; stg; wt; \
    BAR(); WAITKL(); \
    __builtin_amdgcn_s_setprio(1); \
    MFMA16(mb); \
    __builtin_amdgcn_s_setprio(0); \
    BAR(); \
} while (0)

__global__ __launch_bounds__(512, 2) void gemm_mse_kernel(
        const unsigned short* __restrict__ A,  // x as bf16, stride LDAB
        const unsigned short* __restrict__ B,  // W as bf16, stride LDAB
        const float* __restrict__ Y,           // [MDIM,VDIM] fp32
        float* __restrict__ out) {
    __shared__ __align__(16) unsigned short As[2][BM * BK];  // 64 KB
    __shared__ __align__(16) unsigned short Bs[2][BN * BK];  // 64 KB

    const int tid  = threadIdx.x;
    const int lane = tid & 63;
    const int wid  = tid >> 6;            // 0..7
    const int wrow = (wid >> 2) * 128;    // wave M offset in tile
    const int wcol = (wid & 3) * 64;      // wave V offset in tile
    const int m0 = lane & 15;
    const int q  = lane >> 4;             // 0..3

    // XCD-aware bijective swizzle: 1000 blocks, 1000 % 8 == 0.
    const int lin = blockIdx.x;                   // 0..999
    const int swz = (lin & 7) * 125 + (lin >> 3); // each XCD: 125 contiguous
    const int tm = swz & 7;                       // 8 M tiles (fast)
    const int tv = swz >> 3;                      // 125 V tiles (slow)
    const long rowBase = (long)tm * BM;
    const long colBase = (long)tv * BN;

    f32x4 acc[8][4];
#pragma unroll
    for (int i = 0; i < 8; ++i)
#pragma unroll
        for (int j = 0; j < 4; ++j)
            acc[i][j] = (f32x4){0.f, 0.f, 0.f, 0.f};

    // Staging addressing: half-tile = 128 rows x 64 bf16 = 16 KB = 1024 slots
    // of 16B; 512 threads x 2 slots. Slot l: row=l>>3, stored seg=l&7, global
    // seg=(l&7)^(row&7). LDS dest stays linear (tid*16) -> wave-uniform +
    // lane*16 as global_load_lds requires; swizzle lives in the global src.
    const int l0 = tid, l1 = tid + 512;
    const int r0 = l0 >> 3, r1 = l1 >> 3;          // 0..63 / 64..127
    const int g0 = (l0 & 7) ^ (r0 & 7), g1 = (l1 & 7) ^ (r1 & 7);
    const unsigned short* aG0 = A + (size_t)(rowBase + r0) * LDAB + g0 * 8;
    const unsigned short* aG1 = A + (size_t)(rowBase + r1) * LDAB + g1 * 8;
    const unsigned short* bG0 = B + (size_t)(colBase + r0) * LDAB + g0 * 8;
    const unsigned short* bG1 = B + (size_t)(colBase + r1) * LDAB + g1 * 8;
    const int dOff0 = l0 * 8, dOff1 = l1 * 8;      // LDS offsets in shorts

    // Fragment read offsets: global seg for (k-half h, quad q) is h*4+q,
    // stored at (h*4+q) ^ (row&7); row&7 == m0&7 (wrow, mb*16 are mult of 8).
    const int sxor = m0 & 7;
    const int off0 = ((0 + q) ^ sxor) * 8;
    const int off1 = ((4 + q) ^ sxor) * 8;

    bf16x8 af[4];   // A frags: current m-pair x 2 k-halves
    bf16x8 bfr[8];  // B frags: 4 n x 2 k-halves, resident per K-tile

    // Prologue: T0 full (8 loads) + T1.B (4 loads); vmcnt(4) => T0 landed.
    STAGE_A(0, 0, 0); STAGE_A(0, 1, 0);
    STAGE_B(0, 0, 0); STAGE_B(0, 1, 0);
    STAGE_B(1, 0, BK); STAGE_B(1, 1, BK);
    VMCNT4();
    BAR();

    for (int i = 0; i < 16; ++i) {
        const int ktb  = i * 2 * BK;     // k of tile 2i
        const int ktA1 = ktb + BK;       // tile 2i+1 (always valid)
        int ktN  = ktb + 2 * BK;         // tile 2i+2 (clamp on last iter)
        if (ktN  > KDIM - BK) ktN  = KDIM - BK;
        int ktN1 = ktb + 3 * BK;         // tile 2i+3 (clamp on last iter)
        if (ktN1 > KDIM - BK) ktN1 = KDIM - BK;

        // ph0..ph3: compute tile 2i from buf0
        PHASE({ DS_B8(0); DS_A2(0, 0); },
              { STAGE_A(1, 0, ktA1); STAGE_A(1, 1, ktA1); }, , 0, 0);
        PHASE(DS_A2(0, 2), STAGE_B(0, 0, ktN), , 0, 2);
        PHASE(DS_A2(0, 4), STAGE_B(0, 1, ktN), , 0, 4);
        PHASE(DS_A2(0, 6), , VMCNT4(), 0, 6);
        // ph4..ph7: compute tile 2i+1 from buf1
        PHASE({ DS_B8(1); DS_A2(1, 0); }, STAGE_A(0, 0, ktN), , 1, 0);
        PHASE(DS_A2(1, 2), STAGE_A(0, 1, ktN), , 1, 2);
        PHASE(DS_A2(1, 4), STAGE_B(1, 0, ktN1), , 1, 4);
        PHASE(DS_A2(1, 6), STAGE_B(1, 1, ktN1), VMCNT4(), 1, 6);
    }

    VMCNT0();  // drain clamped tail stages before reusing LDS
    BAR();

    // Fused MSE epilogue. C/D layout: col = lane&15, row = (lane>>4)*4 + reg.
    float sum = 0.f;
#pragma unroll
    for (int m = 0; m < 8; ++m) {
#pragma unroll
        for (int n = 0; n < 4; ++n) {
            long gr = rowBase + wrow + m * 16 + q * 4;
            long gc = colBase + wcol + n * 16 + m0;
            const float* yp = Y + gr * (long)VDIM + gc;
#pragma unroll
            for (int r = 0; r < 4; ++r) {
                float d = acc[m][n][r] - yp[(long)r * VDIM];
                sum += d * d;
            }
        }
    }
    sum += __shfl_down(sum, 32);
    sum += __shfl_down(sum, 16);
    sum += __shfl_down(sum, 8);
    sum += __shfl_down(sum, 4);
    sum += __shfl_down(sum, 2);
    sum += __shfl_down(sum, 1);
    float* red = (float*)(void*)As;
    if (lane == 0) red[wid] = sum;
    __syncthreads();
    if (tid == 0) {
        float t = 0.f;
#pragma unroll
        for (int w = 0; w < 8; ++w) t += red[w];
        atomicAdd(out, t * (1.0f / ((float)MDIM * (float)VDIM)));
    }
}

extern "C" void kernel_launch(void* const* d_in, const int* in_sizes, int n_in,
                              void* d_out, int out_size, void* d_ws, size_t ws_size,
                              hipStream_t stream) {
    float* x = (float*)d_in[0];              // [2048, 2048]  (in-place cast)
    const float* y = (const float*)d_in[1];  // [2048, 32000]
    float* W = (float*)d_in[2];              // [32000, 2048] (in-place cast)
    float* out = (float*)d_out;
    (void)d_ws; (void)ws_size;

    cast_inplace_rows4_kernel<<<MDIM / 4, 256, 0, stream>>>(x, out);  // also zeroes out
    cast_inplace_rows4_kernel<<<VDIM / 4, 256, 0, stream>>>(W, nullptr);

    dim3 grid((MDIM / BM) * (VDIM / BN));  // 1000 blocks, swizzled in-kernel
    gemm_mse_kernel<<<grid, 512, 0, stream>>>(
        (const unsigned short*)x, (const unsigned short*)W, y, out);
}